// Round 11
// baseline (303.453 us; speedup 1.0000x reference)
//
#include <hip/hip_runtime.h>
#include <hip/hip_fp16.h>
#include <hip/hip_cooperative_groups.h>

namespace cg = cooperative_groups;

#define NN 100000
#define NE 1600000
#define ETOT (NE + NN)          // 1,700,000 CSR entries
#define FIN 128
#define FHID 128
#define FOUT 16

#define NB1 196                 // CSR-build buckets of 512 nodes (dst>>9)
#define PBLK 256                // partition blocks
#define PCH (NE / PBLK)         // 6250 edges per partition block (exact)
#define P2_CAP 10240            // ord capacity (avg bucket tot ~8700, sigma~90)

typedef _Float16 f16x8 __attribute__((ext_vector_type(8)));
typedef float f32x4 __attribute__((ext_vector_type(4)));

// ---- R11: whole graph build (R7's 3-pass partition + in-bucket CSR) plus
// W1 transpose fused into ONE cooperative kernel. 6 dispatches -> 1; phases
// separated by grid.sync(); per-phase logic identical to the R10 kernels. ----

__global__ __launch_bounds__(256) void k_buildall(const int* __restrict__ ei,
                                                  const float* __restrict__ W1,
                                                  int* __restrict__ cnt,
                                                  int* __restrict__ woffp,
                                                  int* __restrict__ bintot,
                                                  int* __restrict__ binstart,
                                                  int* __restrict__ rowptr,
                                                  float* __restrict__ dinv,
                                                  unsigned* __restrict__ binned,
                                                  int* __restrict__ col,
                                                  _Float16* __restrict__ WT) {
    cg::grid_group grid = cg::this_grid();
    __shared__ int dcnt[512];
    __shared__ int pref[512];
    __shared__ int sc[256];
    __shared__ int ord[P2_CAP];                   // 40 KB (45 KB total -> 3 blk/CU)
    int tid = threadIdx.x;
    int blk = blockIdx.x;
    const int* dst = ei + NE;
    int e0 = blk * PCH;

    // ---- phase 1: per-(block,bin) histogram (all 256 blocks) ----
    {
        int* h = dcnt;                            // 196 ints
        for (int i = tid; i < NB1; i += 256) h[i] = 0;
        __syncthreads();
        for (int e = e0 + tid; e < e0 + PCH; e += 256)
            atomicAdd(&h[dst[e] >> 9], 1);
        __syncthreads();
        for (int i = tid; i < NB1; i += 256) cnt[blk * NB1 + i] = h[i];
    }
    grid.sync();

    // ---- phase 2: per-bin scan over 256 block counts (blocks 0..195) ----
    if (blk < NB1) {
        int v = cnt[tid * NB1 + blk];
        sc[tid] = v;
        __syncthreads();
        for (int off = 1; off < 256; off <<= 1) {
            int xv = (tid >= off) ? sc[tid - off] : 0;
            __syncthreads();
            sc[tid] += xv;
            __syncthreads();
        }
        woffp[tid * NB1 + blk] = sc[tid] - v;     // exclusive
        if (tid == 255) bintot[blk] = sc[255];
    }
    grid.sync();

    // ---- phase 3: binstart scan (block 0) | W1 transpose (blocks 1..8) ----
    if (blk == 0) {
        int v = (tid < NB1) ? bintot[tid] : 0;
        sc[tid] = v;
        __syncthreads();
        for (int off = 1; off < 256; off <<= 1) {
            int xv = (tid >= off) ? sc[tid - off] : 0;
            __syncthreads();
            sc[tid] += xv;
            __syncthreads();
        }
        if (tid < NB1) binstart[tid] = sc[tid] - v;
        if (tid == NB1 - 1) binstart[NB1] = sc[tid];   // == NE
        if (tid == 0) rowptr[NN] = ETOT;
    } else if (blk <= 8) {
        _Float16* tl = (_Float16*)ord;            // [16][136] overlay
        int b = blk - 1;
        #pragma unroll
        for (int i = 0; i < 8; ++i) {             // coalesced 16x128 stripe
            int idx = tid + i * 256;
            int k = idx >> 7, n = idx & 127;
            tl[k * 136 + n] = (_Float16)W1[(b * 16 + k) * FHID + n];
        }
        __syncthreads();
        #pragma unroll
        for (int i = 0; i < 8; ++i) {
            int idx = tid + i * 256;
            int n = idx >> 4, k = idx & 15;
            WT[n * FIN + b * 16 + k] = tl[k * 136 + n];
        }
    }
    grid.sync();

    // ---- phase 4: scatter packed (src | dloc<<17) records (all blocks) ----
    {
        int* cur = dcnt;                          // 196 ints
        for (int i = tid; i < NB1; i += 256)
            cur[i] = binstart[i] + woffp[blk * NB1 + i];
        __syncthreads();
        for (int e = e0 + tid; e < e0 + PCH; e += 256) {
            int s = ei[e], d = dst[e];
            int b = d >> 9;
            int pos = atomicAdd(&cur[b], 1);
            binned[pos] = (unsigned)s | ((unsigned)(d & 511) << 17);
        }
    }
    grid.sync();

    // ---- phase 5: per-bucket CSR build (blocks 0..195) ----
    if (blk < NB1) {
        int n0 = blk * 512;
        int nn = min(512, NN - n0);
        int eb = binstart[blk];
        int ecnt = binstart[blk + 1] - eb;        // edges in bucket
        int colbase = eb + n0;                    // + self loops before bucket
        dcnt[tid] = 0; dcnt[tid + 256] = 0;
        __syncthreads();
        for (int e = tid; e < ecnt; e += 256)     // per-node edge counts
            atomicAdd(&dcnt[binned[eb + e] >> 17], 1);
        __syncthreads();
        int d0 = (2 * tid < nn)     ? dcnt[2 * tid] + 1     : 0;   // +1 self loop
        int d1 = (2 * tid + 1 < nn) ? dcnt[2 * tid + 1] + 1 : 0;
        sc[tid] = d0 + d1;
        __syncthreads();
        for (int off = 1; off < 256; off <<= 1) { // inclusive scan of pairs
            int xv = (tid >= off) ? sc[tid - off] : 0;
            __syncthreads();
            sc[tid] += xv;
            __syncthreads();
        }
        int base = sc[tid] - d0 - d1;             // exclusive
        pref[2 * tid] = base;
        pref[2 * tid + 1] = base + d0;
        __syncthreads();
        for (int i = tid; i < nn; i += 256) {     // rowptr, dinv, self loop
            int p = pref[i];
            rowptr[n0 + i] = colbase + p;
            dinv[n0 + i] = rsqrtf((float)(dcnt[i] + 1));
            ord[p] = n0 + i;                      // self loop at slot 0
        }
        __syncthreads();
        for (int i = tid; i < nn; i += 256) dcnt[i] = pref[i] + 1;  // cursors
        __syncthreads();
        for (int e = tid; e < ecnt; e += 256) {   // edges
            unsigned p = binned[eb + e];
            int pos = atomicAdd(&dcnt[p >> 17], 1);
            int sv = (int)(p & 0x1FFFFu);
            if (pos < P2_CAP) ord[pos] = sv; else col[colbase + pos] = sv;
        }
        __syncthreads();
        int tot = ecnt + nn;
        int lim = min(tot, P2_CAP);
        for (int i = tid; i < lim; i += 256) col[colbase + i] = ord[i];
    }
}

// ---------------- GEMM1 (MFMA fp16): g = dinv .* (x @ W1) -> fp16 [NN][128] ----

__global__ __launch_bounds__(256) void k_gemm1(const float* __restrict__ x,
                                               const _Float16* __restrict__ WT,
                                               const float* __restrict__ dinv,
                                               _Float16* __restrict__ h) {
    __shared__ _Float16 xs[64 * 128];
    __shared__ _Float16 ws[128 * 128];
    int tid = threadIdx.x;
    int m0 = blockIdx.x * 64;
    #pragma unroll
    for (int i = 0; i < 4; ++i) {                 // x tile: 64 rows x 128 k
        int u = tid + i * 256;
        int r = u >> 4;
        int k0 = (u & 15) * 8;
        int row = m0 + r;
        f16x8 v = {};
        if (row < NN) {
            float4 a = *(const float4*)&x[(size_t)row * FIN + k0];
            float4 b = *(const float4*)&x[(size_t)row * FIN + k0 + 4];
            v[0] = (_Float16)a.x; v[1] = (_Float16)a.y;
            v[2] = (_Float16)a.z; v[3] = (_Float16)a.w;
            v[4] = (_Float16)b.x; v[5] = (_Float16)b.y;
            v[6] = (_Float16)b.z; v[7] = (_Float16)b.w;
        }
        *(f16x8*)&xs[r * 128 + (k0 ^ ((r & 7) * 8))] = v;
    }
    #pragma unroll
    for (int i = 0; i < 8; ++i) {                 // W tile: 128 n x 128 k
        int u = tid + i * 256;
        int n = u >> 4;
        int k0 = (u & 15) * 8;
        f16x8 v = *(const f16x8*)&WT[n * FIN + k0];
        *(f16x8*)&ws[n * 128 + (k0 ^ ((n & 7) * 8))] = v;
    }
    __syncthreads();
    int wave = tid >> 6, lane = tid & 63;
    int lm = lane & 15, lg = lane >> 4;
    f32x4 acc[8];
    #pragma unroll
    for (int t = 0; t < 8; ++t) acc[t] = (f32x4){0.f, 0.f, 0.f, 0.f};
    int am = wave * 16 + lm;                      // A row within tile
    #pragma unroll
    for (int s = 0; s < 4; ++s) {                 // K steps of 32
        int ka = s * 32 + lg * 8;
        f16x8 af = *(const f16x8*)&xs[am * 128 + (ka ^ ((am & 7) * 8))];
        #pragma unroll
        for (int t = 0; t < 8; ++t) {
            int bn = t * 16 + lm;
            f16x8 bf = *(const f16x8*)&ws[bn * 128 + (ka ^ ((bn & 7) * 8))];
            acc[t] = __builtin_amdgcn_mfma_f32_16x16x32_f16(af, bf, acc[t], 0, 0, 0);
        }
    }
    float dsc[4];
    #pragma unroll
    for (int r = 0; r < 4; ++r) {                 // row scale (broadcast loads)
        int grow = m0 + wave * 16 + lg * 4 + r;
        dsc[r] = (grow < NN) ? dinv[grow] : 0.f;
    }
    #pragma unroll
    for (int t = 0; t < 8; ++t) {
        int coln = t * 16 + lm;
        #pragma unroll
        for (int r = 0; r < 4; ++r) {
            int grow = m0 + wave * 16 + lg * 4 + r;
            if (grow < NN)
                h[(size_t)grow * FHID + coln] = (_Float16)(acc[t][r] * dsc[r]);
        }
    }
}

// ---------------- aggregation helpers ----------------

__device__ __forceinline__ void add_row8(float* acc, int4 raw) {
    const __half2* p = reinterpret_cast<const __half2*>(&raw);
    #pragma unroll
    for (int j = 0; j < 4; ++j) {
        float2 f = __half22float2(p[j]);
        acc[2 * j]     += f.x;
        acc[2 * j + 1] += f.y;
    }
}

// ---------------- Agg1 + bias + ReLU -> out1 fp16 [NN][64] half2 ----------------
// At the random-gather fabric roofline (~3.5 TB/s, FETCH ~190MB) per R10.

__global__ __launch_bounds__(256) void k_agg1(const __half2* __restrict__ hf,
                                              const int* __restrict__ rowptr,
                                              const int* __restrict__ col,
                                              const float* __restrict__ dinv,
                                              const float* __restrict__ b1,
                                              __half2* __restrict__ out1) {
    int tid = threadIdx.x;
    int node = blockIdx.x * 16 + (tid >> 4);      // grid 6250 exact
    int lane = tid & 15;                          // features lane*8 .. lane*8+7
    int beg = rowptr[node];
    int end = rowptr[node + 1];
    float acc[8] = {};
    int e = beg;
    for (; e + 4 <= end; e += 4) {
        int s0 = col[e], s1 = col[e + 1], s2 = col[e + 2], s3 = col[e + 3];
        int4 r0 = *reinterpret_cast<const int4*>(hf + (size_t)s0 * 64 + lane * 4);
        int4 r1 = *reinterpret_cast<const int4*>(hf + (size_t)s1 * 64 + lane * 4);
        int4 r2 = *reinterpret_cast<const int4*>(hf + (size_t)s2 * 64 + lane * 4);
        int4 r3 = *reinterpret_cast<const int4*>(hf + (size_t)s3 * 64 + lane * 4);
        add_row8(acc, r0);
        add_row8(acc, r1);
        add_row8(acc, r2);
        add_row8(acc, r3);
    }
    for (; e < end; ++e) {
        int s = col[e];
        int4 r = *reinterpret_cast<const int4*>(hf + (size_t)s * 64 + lane * 4);
        add_row8(acc, r);
    }
    float di = dinv[node];
    float4 bA = *(const float4*)&b1[lane * 8];
    float4 bB = *(const float4*)&b1[lane * 8 + 4];
    float o[8];
    o[0] = fmaxf(acc[0] * di + bA.x, 0.f);
    o[1] = fmaxf(acc[1] * di + bA.y, 0.f);
    o[2] = fmaxf(acc[2] * di + bA.z, 0.f);
    o[3] = fmaxf(acc[3] * di + bA.w, 0.f);
    o[4] = fmaxf(acc[4] * di + bB.x, 0.f);
    o[5] = fmaxf(acc[5] * di + bB.y, 0.f);
    o[6] = fmaxf(acc[6] * di + bB.z, 0.f);
    o[7] = fmaxf(acc[7] * di + bB.w, 0.f);
    __half2 ph[4];
    #pragma unroll
    for (int j = 0; j < 4; ++j) ph[j] = __floats2half2_rn(o[2 * j], o[2 * j + 1]);
    *reinterpret_cast<int4*>(out1 + (size_t)node * 64 + lane * 4) =
        *reinterpret_cast<int4*>(ph);
}

// ---------------- GEMM2: g2 = dinv .* (out1 @ W2) -> fp16 [NN][8] half2 --------

__global__ __launch_bounds__(256) void k_gemm2(const __half2* __restrict__ a,
                                               const float* __restrict__ W,
                                               const float* __restrict__ dinv,
                                               __half2* __restrict__ h2) {
    __shared__ __half2 xs[64][68];                // 64 rows x 64 half2 (+4 pad)
    __shared__ float ws[FHID][FOUT];
    int tid = threadIdx.x;
    int m0 = blockIdx.x * 64;
    #pragma unroll
    for (int i = 0; i < 8; ++i) {                 // W2: 128x16
        int idx = tid + i * 256;
        ws[idx >> 4][idx & 15] = W[idx];
    }
    #pragma unroll
    for (int i = 0; i < 4; ++i) {                 // a tile: 64 rows x 16 int4
        int idx = tid + i * 256;
        int r = idx >> 4, q = idx & 15;
        int row = m0 + r;
        int4 v = make_int4(0, 0, 0, 0);
        if (row < NN) v = *reinterpret_cast<const int4*>(a + (size_t)row * 64 + q * 4);
        *reinterpret_cast<int4*>(&xs[r][q * 4]) = v;
    }
    __syncthreads();
    int cp = tid & 7, r = tid >> 3;               // r in 0..31
    float a00 = 0.f, a01 = 0.f, a10 = 0.f, a11 = 0.f;
    #pragma unroll 8
    for (int k2 = 0; k2 < 64; ++k2) {
        float2 f0 = __half22float2(xs[r][k2]);
        float2 f1 = __half22float2(xs[r + 32][k2]);
        float wa0 = ws[2 * k2][2 * cp],     wb0 = ws[2 * k2][2 * cp + 1];
        float wa1 = ws[2 * k2 + 1][2 * cp], wb1 = ws[2 * k2 + 1][2 * cp + 1];
        a00 += f0.x * wa0 + f0.y * wa1;
        a01 += f0.x * wb0 + f0.y * wb1;
        a10 += f1.x * wa0 + f1.y * wa1;
        a11 += f1.x * wb0 + f1.y * wb1;
    }
    int row0 = m0 + r, row1 = m0 + r + 32;
    if (row0 < NN) {
        float d = dinv[row0];
        h2[(size_t)row0 * 8 + cp] = __floats2half2_rn(a00 * d, a01 * d);
    }
    if (row1 < NN) {
        float d = dinv[row1];
        h2[(size_t)row1 * 8 + cp] = __floats2half2_rn(a10 * d, a11 * d);
    }
}

// ---------------- Agg2 + bias -> out fp32 ----------------

__global__ __launch_bounds__(256) void k_agg2(const __half2* __restrict__ h2,
                                              const int* __restrict__ rowptr,
                                              const int* __restrict__ col,
                                              const float* __restrict__ dinv,
                                              const float* __restrict__ b2,
                                              float* __restrict__ out) {
    int tid = threadIdx.x;
    int node = blockIdx.x * 128 + (tid >> 1);
    if (node >= NN) return;
    int l = tid & 1;                              // features l*8 .. l*8+7
    int beg = rowptr[node];
    int end = rowptr[node + 1];
    float acc[8] = {};
    int e = beg;
    for (; e + 4 <= end; e += 4) {
        int s0 = col[e], s1 = col[e + 1], s2 = col[e + 2], s3 = col[e + 3];
        int4 r0 = *reinterpret_cast<const int4*>(h2 + (size_t)s0 * 8 + l * 4);
        int4 r1 = *reinterpret_cast<const int4*>(h2 + (size_t)s1 * 8 + l * 4);
        int4 r2 = *reinterpret_cast<const int4*>(h2 + (size_t)s2 * 8 + l * 4);
        int4 r3 = *reinterpret_cast<const int4*>(h2 + (size_t)s3 * 8 + l * 4);
        add_row8(acc, r0);
        add_row8(acc, r1);
        add_row8(acc, r2);
        add_row8(acc, r3);
    }
    for (; e < end; ++e) {
        int s = col[e];
        int4 r = *reinterpret_cast<const int4*>(h2 + (size_t)s * 8 + l * 4);
        add_row8(acc, r);
    }
    float di = dinv[node];
    float4 bA = *(const float4*)&b2[l * 8];
    float4 bB = *(const float4*)&b2[l * 8 + 4];
    float4 oA, oB;
    oA.x = acc[0] * di + bA.x;  oA.y = acc[1] * di + bA.y;
    oA.z = acc[2] * di + bA.z;  oA.w = acc[3] * di + bA.w;
    oB.x = acc[4] * di + bB.x;  oB.y = acc[5] * di + bB.y;
    oB.z = acc[6] * di + bB.z;  oB.w = acc[7] * di + bB.w;
    *(float4*)&out[(size_t)node * 16 + l * 8] = oA;
    *(float4*)&out[(size_t)node * 16 + l * 8 + 4] = oB;
}

// ---------------- launch ----------------

extern "C" void kernel_launch(void* const* d_in, const int* in_sizes, int n_in,
                              void* d_out, int out_size, void* d_ws, size_t ws_size,
                              hipStream_t stream) {
    const float* x  = (const float*)d_in[0];
    const int*   ei = (const int*)d_in[1];       // [2][NE]: row0=src, row1=dst
    const float* W1 = (const float*)d_in[2];
    const float* b1 = (const float*)d_in[3];
    const float* W2 = (const float*)d_in[4];
    const float* b2 = (const float*)d_in[5];
    float* out = (float*)d_out;

    char* ws = (char*)d_ws;
    size_t off = 0;
    #define WS_ALLOC(ptr_t, name, bytes) \
        ptr_t name = (ptr_t)(ws + off); off = (off + (size_t)(bytes) + 511) & ~(size_t)511;
    WS_ALLOC(int*,       rowptr,   ((size_t)NN + 1) * 4)
    WS_ALLOC(int*,       cnt,      (size_t)PBLK * NB1 * 4)
    WS_ALLOC(int*,       woffp,    (size_t)PBLK * NB1 * 4)
    WS_ALLOC(int*,       bintot,   (size_t)NB1 * 4)
    WS_ALLOC(int*,       binstart, ((size_t)NB1 + 1) * 4)
    WS_ALLOC(int*,       colv,     (size_t)ETOT * 4)
    WS_ALLOC(float*,     dinv,     (size_t)NN * 4)
    WS_ALLOC(_Float16*,  w1t,      (size_t)FIN * FHID * 2)
    WS_ALLOC(_Float16*,  hf,       (size_t)NN * FHID * 2)
    WS_ALLOC(__half2*,   out1f,    (size_t)NN * FHID * 2)
    WS_ALLOC(__half2*,   h2f,     (size_t)NN * FOUT * 2)
    #undef WS_ALLOC
    (void)ws_size; (void)in_sizes; (void)n_in; (void)out_size;

    // binned records (6.8MB) alias the hf region (dead until k_gemm1,
    // consumed inside k_buildall phase 5, which completes before k_gemm1).
    unsigned* binned = (unsigned*)hf;

    // fused graph build + W1 transpose (cooperative, 5 grid phases)
    {
        void* args[] = {(void*)&ei, (void*)&W1, (void*)&cnt, (void*)&woffp,
                        (void*)&bintot, (void*)&binstart, (void*)&rowptr,
                        (void*)&dinv, (void*)&binned, (void*)&colv, (void*)&w1t};
        hipLaunchCooperativeKernel((const void*)k_buildall, dim3(PBLK), dim3(256),
                                   args, 0, stream);
    }

    // layer 1
    k_gemm1<<<(NN + 63) / 64, 256, 0, stream>>>(x, w1t, dinv, hf);
    k_agg1<<<NN / 16, 256, 0, stream>>>((const __half2*)hf, rowptr, colv, dinv, b1, out1f);

    // layer 2
    k_gemm2<<<(NN + 63) / 64, 256, 0, stream>>>(out1f, W2, dinv, h2f);
    k_agg2<<<(NN + 127) / 128, 256, 0, stream>>>(h2f, rowptr, colv, dinv, b2, out);
}

// Round 12
// 167.334 us; speedup vs baseline: 1.8134x; 1.8134x over previous
//
#include <hip/hip_runtime.h>
#include <hip/hip_fp16.h>

#define NN 100000
#define NE 1600000
#define ETOT (NE + NN)          // 1,700,000 CSR entries
#define FIN 128
#define FHID 128
#define FOUT 16

#define NB1 196                 // CSR-build buckets of 512 nodes (dst>>9)
#define PBLK 256                // partition blocks
#define PCH (NE / PBLK)         // 6250 edges per partition block (exact)
#define P2_CAP 10240            // ord capacity (avg bucket tot ~8700, sigma~90)

typedef _Float16 f16x8 __attribute__((ext_vector_type(8)));
typedef float f32x4 __attribute__((ext_vector_type(4)));

// ---- graph build: 3-pass dst-partition (R7 structure, R12 consolidation:
// w1t rides in k_cnt's grid tail; bintot scans recomputed in-block so the
// k_bstart dispatch disappears; R11 showed grid.sync costs >> extra scans) ----

// Pass A: per-(block,bin) histogram (blocks 0..255) + W1 transpose (256..263).
__global__ __launch_bounds__(256) void k_cnt(const int* __restrict__ ei,
                                             const float* __restrict__ W1,
                                             int* __restrict__ cnt,
                                             _Float16* __restrict__ WT) {
    int tid = threadIdx.x, blk = blockIdx.x;
    if (blk < PBLK) {
        __shared__ int h[NB1];
        for (int i = tid; i < NB1; i += 256) h[i] = 0;
        __syncthreads();
        const int* dst = ei + NE;
        int e0 = blk * PCH;
        for (int e = e0 + tid; e < e0 + PCH; e += 256)
            atomicAdd(&h[dst[e] >> 9], 1);
        __syncthreads();
        for (int i = tid; i < NB1; i += 256) cnt[blk * NB1 + i] = h[i];
    } else {
        __shared__ _Float16 tl[16][136];
        int b = blk - PBLK;
        #pragma unroll
        for (int i = 0; i < 8; ++i) {             // coalesced 16x128 stripe
            int idx = tid + i * 256;
            int k = idx >> 7, n = idx & 127;
            tl[k][n] = (_Float16)W1[(b * 16 + k) * FHID + n];
        }
        __syncthreads();
        #pragma unroll
        for (int i = 0; i < 8; ++i) {
            int idx = tid + i * 256;
            int n = idx >> 4, k = idx & 15;
            WT[n * FIN + b * 16 + k] = tl[k][n];
        }
    }
}

// Pass B: per-bin exclusive scan over the 256 block counts + bin totals.
__global__ __launch_bounds__(256) void k_offs(const int* __restrict__ cnt,
                                              int* __restrict__ woffp,
                                              int* __restrict__ bintot,
                                              int* __restrict__ rowptr) {
    __shared__ int s[256];
    int b = blockIdx.x;
    int t = threadIdx.x;
    int v = cnt[t * NB1 + b];
    s[t] = v;
    __syncthreads();
    for (int off = 1; off < 256; off <<= 1) {
        int xv = (t >= off) ? s[t - off] : 0;
        __syncthreads();
        s[t] += xv;
        __syncthreads();
    }
    woffp[t * NB1 + b] = s[t] - v;                // exclusive
    if (t == 255) bintot[b] = s[255];
    if (b == 0 && t == 0) rowptr[NN] = ETOT;
}

// Pass C: scatter packed (src | dloc<<17) records into per-(block,bin)
// contiguous segments. Preamble scans bintot in-block (replaces k_bstart).
__global__ __launch_bounds__(256) void k_scat(const int* __restrict__ ei,
                                              const int* __restrict__ woffp,
                                              const int* __restrict__ bintot,
                                              unsigned* __restrict__ binned) {
    __shared__ int sc[256];
    __shared__ int cur[NB1];
    int tid = threadIdx.x;
    int k = blockIdx.x;
    int v = (tid < NB1) ? bintot[tid] : 0;
    sc[tid] = v;
    __syncthreads();
    for (int off = 1; off < 256; off <<= 1) {
        int xv = (tid >= off) ? sc[tid - off] : 0;
        __syncthreads();
        sc[tid] += xv;
        __syncthreads();
    }
    if (tid < NB1) cur[tid] = (sc[tid] - v) + woffp[k * NB1 + tid];
    __syncthreads();
    int e0 = k * PCH;
    for (int e = e0 + tid; e < e0 + PCH; e += 256) {
        int s = ei[e], d = ei[NE + e];
        int b = d >> 9;
        int pos = atomicAdd(&cur[b], 1);
        binned[pos] = (unsigned)s | ((unsigned)(d & 511) << 17);
    }
}

// Pass D: one block per bucket. Preamble recomputes its binstart from bintot;
// per-node degree count -> LDS scan -> rowptr/dinv; counting-scatter; stream
// ordered segment to col coalesced.
__global__ __launch_bounds__(256) void k_build(const unsigned* __restrict__ binned,
                                               const int* __restrict__ bintot,
                                               int* __restrict__ rowptr,
                                               float* __restrict__ dinv,
                                               int* __restrict__ col) {
    __shared__ int dcnt[512];
    __shared__ int pref[512];
    __shared__ int sc[256];
    __shared__ int ord[P2_CAP];                   // 40 KB
    int blk = blockIdx.x;
    int tid = threadIdx.x;
    int bv = (tid < NB1) ? bintot[tid] : 0;       // bin prefix scan
    sc[tid] = bv;
    __syncthreads();
    for (int off = 1; off < 256; off <<= 1) {
        int xv = (tid >= off) ? sc[tid - off] : 0;
        __syncthreads();
        sc[tid] += xv;
        __syncthreads();
    }
    int ecnt = bintot[blk];                       // edges in bucket
    int eb = sc[blk] - ecnt;                      // binned base
    __syncthreads();                              // sc reused below
    int n0 = blk * 512;
    int nn = min(512, NN - n0);
    int colbase = eb + n0;                        // + self loops before bucket
    dcnt[tid] = 0; dcnt[tid + 256] = 0;
    __syncthreads();
    for (int e = tid; e < ecnt; e += 256)         // per-node edge counts
        atomicAdd(&dcnt[binned[eb + e] >> 17], 1);
    __syncthreads();
    int d0 = (2 * tid < nn)     ? dcnt[2 * tid] + 1     : 0;   // +1 self loop
    int d1 = (2 * tid + 1 < nn) ? dcnt[2 * tid + 1] + 1 : 0;
    sc[tid] = d0 + d1;
    __syncthreads();
    for (int off = 1; off < 256; off <<= 1) {     // inclusive scan of pairs
        int xv = (tid >= off) ? sc[tid - off] : 0;
        __syncthreads();
        sc[tid] += xv;
        __syncthreads();
    }
    int base = sc[tid] - d0 - d1;                 // exclusive
    pref[2 * tid] = base;
    pref[2 * tid + 1] = base + d0;
    __syncthreads();
    for (int i = tid; i < nn; i += 256) {         // rowptr, dinv, self loop
        int p = pref[i];
        rowptr[n0 + i] = colbase + p;
        dinv[n0 + i] = rsqrtf((float)(dcnt[i] + 1));
        ord[p] = n0 + i;                          // self loop at slot 0
    }
    __syncthreads();
    for (int i = tid; i < nn; i += 256) dcnt[i] = pref[i] + 1;  // cursors
    __syncthreads();
    for (int e = tid; e < ecnt; e += 256) {       // edges
        unsigned p = binned[eb + e];
        int pos = atomicAdd(&dcnt[p >> 17], 1);
        int sv = (int)(p & 0x1FFFFu);
        if (pos < P2_CAP) ord[pos] = sv; else col[colbase + pos] = sv;
    }
    __syncthreads();
    int tot = ecnt + nn;
    int lim = min(tot, P2_CAP);
    for (int i = tid; i < lim; i += 256) col[colbase + i] = ord[i];
}

// ---------------- GEMM1 (MFMA fp16): g = dinv .* (x @ W1) -> fp16 [NN][128] ----

__global__ __launch_bounds__(256) void k_gemm1(const float* __restrict__ x,
                                               const _Float16* __restrict__ WT,
                                               const float* __restrict__ dinv,
                                               _Float16* __restrict__ h) {
    __shared__ _Float16 xs[64 * 128];
    __shared__ _Float16 ws[128 * 128];
    int tid = threadIdx.x;
    int m0 = blockIdx.x * 64;
    #pragma unroll
    for (int i = 0; i < 4; ++i) {                 // x tile: 64 rows x 128 k
        int u = tid + i * 256;
        int r = u >> 4;
        int k0 = (u & 15) * 8;
        int row = m0 + r;
        f16x8 v = {};
        if (row < NN) {
            float4 a = *(const float4*)&x[(size_t)row * FIN + k0];
            float4 b = *(const float4*)&x[(size_t)row * FIN + k0 + 4];
            v[0] = (_Float16)a.x; v[1] = (_Float16)a.y;
            v[2] = (_Float16)a.z; v[3] = (_Float16)a.w;
            v[4] = (_Float16)b.x; v[5] = (_Float16)b.y;
            v[6] = (_Float16)b.z; v[7] = (_Float16)b.w;
        }
        *(f16x8*)&xs[r * 128 + (k0 ^ ((r & 7) * 8))] = v;
    }
    #pragma unroll
    for (int i = 0; i < 8; ++i) {                 // W tile: 128 n x 128 k
        int u = tid + i * 256;
        int n = u >> 4;
        int k0 = (u & 15) * 8;
        f16x8 v = *(const f16x8*)&WT[n * FIN + k0];
        *(f16x8*)&ws[n * 128 + (k0 ^ ((n & 7) * 8))] = v;
    }
    __syncthreads();
    int wave = tid >> 6, lane = tid & 63;
    int lm = lane & 15, lg = lane >> 4;
    f32x4 acc[8];
    #pragma unroll
    for (int t = 0; t < 8; ++t) acc[t] = (f32x4){0.f, 0.f, 0.f, 0.f};
    int am = wave * 16 + lm;                      // A row within tile
    #pragma unroll
    for (int s = 0; s < 4; ++s) {                 // K steps of 32
        int ka = s * 32 + lg * 8;
        f16x8 af = *(const f16x8*)&xs[am * 128 + (ka ^ ((am & 7) * 8))];
        #pragma unroll
        for (int t = 0; t < 8; ++t) {
            int bn = t * 16 + lm;
            f16x8 bf = *(const f16x8*)&ws[bn * 128 + (ka ^ ((bn & 7) * 8))];
            acc[t] = __builtin_amdgcn_mfma_f32_16x16x32_f16(af, bf, acc[t], 0, 0, 0);
        }
    }
    float dsc[4];
    #pragma unroll
    for (int r = 0; r < 4; ++r) {                 // row scale (broadcast loads)
        int grow = m0 + wave * 16 + lg * 4 + r;
        dsc[r] = (grow < NN) ? dinv[grow] : 0.f;
    }
    #pragma unroll
    for (int t = 0; t < 8; ++t) {
        int coln = t * 16 + lm;
        #pragma unroll
        for (int r = 0; r < 4; ++r) {
            int grow = m0 + wave * 16 + lg * 4 + r;
            if (grow < NN)
                h[(size_t)grow * FHID + coln] = (_Float16)(acc[t][r] * dsc[r]);
        }
    }
}

// ---------------- aggregation helpers ----------------

__device__ __forceinline__ void add_row8(float* acc, int4 raw) {
    const __half2* p = reinterpret_cast<const __half2*>(&raw);
    #pragma unroll
    for (int j = 0; j < 4; ++j) {
        float2 f = __half22float2(p[j]);
        acc[2 * j]     += f.x;
        acc[2 * j + 1] += f.y;
    }
}

// ---------------- Agg1 + bias + ReLU -> out1 fp16 [NN][64] half2 ----------------
// At the random-gather fabric roofline (~3.5 TB/s, FETCH ~190MB) per R10.

__global__ __launch_bounds__(256) void k_agg1(const __half2* __restrict__ hf,
                                              const int* __restrict__ rowptr,
                                              const int* __restrict__ col,
                                              const float* __restrict__ dinv,
                                              const float* __restrict__ b1,
                                              __half2* __restrict__ out1) {
    int tid = threadIdx.x;
    int node = blockIdx.x * 16 + (tid >> 4);      // grid 6250 exact
    int lane = tid & 15;                          // features lane*8 .. lane*8+7
    int beg = rowptr[node];
    int end = rowptr[node + 1];
    float acc[8] = {};
    int e = beg;
    for (; e + 4 <= end; e += 4) {
        int s0 = col[e], s1 = col[e + 1], s2 = col[e + 2], s3 = col[e + 3];
        int4 r0 = *reinterpret_cast<const int4*>(hf + (size_t)s0 * 64 + lane * 4);
        int4 r1 = *reinterpret_cast<const int4*>(hf + (size_t)s1 * 64 + lane * 4);
        int4 r2 = *reinterpret_cast<const int4*>(hf + (size_t)s2 * 64 + lane * 4);
        int4 r3 = *reinterpret_cast<const int4*>(hf + (size_t)s3 * 64 + lane * 4);
        add_row8(acc, r0);
        add_row8(acc, r1);
        add_row8(acc, r2);
        add_row8(acc, r3);
    }
    for (; e < end; ++e) {
        int s = col[e];
        int4 r = *reinterpret_cast<const int4*>(hf + (size_t)s * 64 + lane * 4);
        add_row8(acc, r);
    }
    float di = dinv[node];
    float4 bA = *(const float4*)&b1[lane * 8];
    float4 bB = *(const float4*)&b1[lane * 8 + 4];
    float o[8];
    o[0] = fmaxf(acc[0] * di + bA.x, 0.f);
    o[1] = fmaxf(acc[1] * di + bA.y, 0.f);
    o[2] = fmaxf(acc[2] * di + bA.z, 0.f);
    o[3] = fmaxf(acc[3] * di + bA.w, 0.f);
    o[4] = fmaxf(acc[4] * di + bB.x, 0.f);
    o[5] = fmaxf(acc[5] * di + bB.y, 0.f);
    o[6] = fmaxf(acc[6] * di + bB.z, 0.f);
    o[7] = fmaxf(acc[7] * di + bB.w, 0.f);
    __half2 ph[4];
    #pragma unroll
    for (int j = 0; j < 4; ++j) ph[j] = __floats2half2_rn(o[2 * j], o[2 * j + 1]);
    *reinterpret_cast<int4*>(out1 + (size_t)node * 64 + lane * 4) =
        *reinterpret_cast<int4*>(ph);
}

// ---------------- GEMM2 (MFMA, R12): h2 = dinv .* (out1 @ W2) -> fp16 [NN][16] --
// R11 post-mortem: scalar-LDS gemm2 was ~384 ds_b32/wave (~20us). MFMA form:
// W2^T staged once (4KB, pad 136 -> 2-way banks only), B-frags live in regs,
// A-frags straight from global (coalesced 16B/lane), 16 mfma per wave.

__global__ __launch_bounds__(256) void k_gemm2(const _Float16* __restrict__ a,
                                               const float* __restrict__ W,
                                               const float* __restrict__ dinv,
                                               _Float16* __restrict__ h2) {
    __shared__ _Float16 w2t[16][136];
    int tid = threadIdx.x;
    #pragma unroll
    for (int i = 0; i < 8; ++i) {                 // stage W2^T (2048 elems)
        int idx = tid + i * 256;                  // idx = k*16 + c
        w2t[idx & 15][idx >> 4] = (_Float16)W[idx];
    }
    __syncthreads();
    int wave = tid >> 6, lane = tid & 63;
    int lm = lane & 15, lg = lane >> 4;
    f16x8 bf[4];
    #pragma unroll
    for (int s = 0; s < 4; ++s)                   // B frags: W2^T col-slice
        bf[s] = *(const f16x8*)&w2t[lm][s * 32 + lg * 8];
    int row0 = blockIdx.x * 256 + wave * 64;
    #pragma unroll
    for (int rt = 0; rt < 4; ++rt) {
        int rbase = row0 + rt * 16;
        f32x4 acc = {0.f, 0.f, 0.f, 0.f};
        #pragma unroll
        for (int s = 0; s < 4; ++s) {
            int arow = rbase + lm;
            f16x8 af = {};
            if (arow < NN)
                af = *(const f16x8*)&a[(size_t)arow * FHID + s * 32 + lg * 8];
            acc = __builtin_amdgcn_mfma_f32_16x16x32_f16(af, bf[s], acc, 0, 0, 0);
        }
        #pragma unroll
        for (int r = 0; r < 4; ++r) {
            int row = rbase + lg * 4 + r;
            if (row < NN)
                h2[(size_t)row * FOUT + lm] = (_Float16)(acc[r] * dinv[row]);
        }
    }
}

// ---------------- Agg2 + bias -> out fp32 ----------------

__global__ __launch_bounds__(256) void k_agg2(const __half2* __restrict__ h2,
                                              const int* __restrict__ rowptr,
                                              const int* __restrict__ col,
                                              const float* __restrict__ dinv,
                                              const float* __restrict__ b2,
                                              float* __restrict__ out) {
    int tid = threadIdx.x;
    int node = blockIdx.x * 128 + (tid >> 1);
    if (node >= NN) return;
    int l = tid & 1;                              // features l*8 .. l*8+7
    int beg = rowptr[node];
    int end = rowptr[node + 1];
    float acc[8] = {};
    int e = beg;
    for (; e + 4 <= end; e += 4) {
        int s0 = col[e], s1 = col[e + 1], s2 = col[e + 2], s3 = col[e + 3];
        int4 r0 = *reinterpret_cast<const int4*>(h2 + (size_t)s0 * 8 + l * 4);
        int4 r1 = *reinterpret_cast<const int4*>(h2 + (size_t)s1 * 8 + l * 4);
        int4 r2 = *reinterpret_cast<const int4*>(h2 + (size_t)s2 * 8 + l * 4);
        int4 r3 = *reinterpret_cast<const int4*>(h2 + (size_t)s3 * 8 + l * 4);
        add_row8(acc, r0);
        add_row8(acc, r1);
        add_row8(acc, r2);
        add_row8(acc, r3);
    }
    for (; e < end; ++e) {
        int s = col[e];
        int4 r = *reinterpret_cast<const int4*>(h2 + (size_t)s * 8 + l * 4);
        add_row8(acc, r);
    }
    float di = dinv[node];
    float4 bA = *(const float4*)&b2[l * 8];
    float4 bB = *(const float4*)&b2[l * 8 + 4];
    float4 oA, oB;
    oA.x = acc[0] * di + bA.x;  oA.y = acc[1] * di + bA.y;
    oA.z = acc[2] * di + bA.z;  oA.w = acc[3] * di + bA.w;
    oB.x = acc[4] * di + bB.x;  oB.y = acc[5] * di + bB.y;
    oB.z = acc[6] * di + bB.z;  oB.w = acc[7] * di + bB.w;
    *(float4*)&out[(size_t)node * 16 + l * 8] = oA;
    *(float4*)&out[(size_t)node * 16 + l * 8 + 4] = oB;
}

// ---------------- launch ----------------

extern "C" void kernel_launch(void* const* d_in, const int* in_sizes, int n_in,
                              void* d_out, int out_size, void* d_ws, size_t ws_size,
                              hipStream_t stream) {
    const float* x  = (const float*)d_in[0];
    const int*   ei = (const int*)d_in[1];       // [2][NE]: row0=src, row1=dst
    const float* W1 = (const float*)d_in[2];
    const float* b1 = (const float*)d_in[3];
    const float* W2 = (const float*)d_in[4];
    const float* b2 = (const float*)d_in[5];
    float* out = (float*)d_out;

    char* ws = (char*)d_ws;
    size_t off = 0;
    #define WS_ALLOC(ptr_t, name, bytes) \
        ptr_t name = (ptr_t)(ws + off); off = (off + (size_t)(bytes) + 511) & ~(size_t)511;
    WS_ALLOC(int*,       rowptr,   ((size_t)NN + 1) * 4)
    WS_ALLOC(int*,       cnt,      (size_t)PBLK * NB1 * 4)
    WS_ALLOC(int*,       woffp,    (size_t)PBLK * NB1 * 4)
    WS_ALLOC(int*,       bintot,   (size_t)NB1 * 4)
    WS_ALLOC(int*,       colv,     (size_t)ETOT * 4)
    WS_ALLOC(float*,     dinv,     (size_t)NN * 4)
    WS_ALLOC(_Float16*,  w1t,      (size_t)FIN * FHID * 2)
    WS_ALLOC(_Float16*,  hf,       (size_t)NN * FHID * 2)
    WS_ALLOC(__half2*,   out1f,    (size_t)NN * FHID * 2)
    WS_ALLOC(_Float16*,  h2f,      (size_t)NN * FOUT * 2)
    #undef WS_ALLOC
    (void)ws_size; (void)in_sizes; (void)n_in; (void)out_size;

    // binned records (6.8MB) alias the hf region (dead until k_gemm1,
    // consumed by k_build which runs before it).
    unsigned* binned = (unsigned*)hf;

    // graph build (8 dispatches total for the whole net)
    k_cnt<<<PBLK + 8, 256, 0, stream>>>(ei, W1, cnt, w1t);
    k_offs<<<NB1, 256, 0, stream>>>(cnt, woffp, bintot, rowptr);
    k_scat<<<PBLK, 256, 0, stream>>>(ei, woffp, bintot, binned);
    k_build<<<NB1, 256, 0, stream>>>(binned, bintot, rowptr, dinv, colv);

    // layer 1
    k_gemm1<<<(NN + 63) / 64, 256, 0, stream>>>(x, w1t, dinv, hf);
    k_agg1<<<NN / 16, 256, 0, stream>>>((const __half2*)hf, rowptr, colv, dinv, b1, out1f);

    // layer 2
    k_gemm2<<<(NN + 255) / 256, 256, 0, stream>>>((const _Float16*)out1f, W2, dinv, h2f);
    k_agg2<<<(NN + 127) / 128, 256, 0, stream>>>((const __half2*)h2f, rowptr, colv, dinv, b2, out);
}